// Round 8
// baseline (160.773 us; speedup 1.0000x reference)
//
#include <hip/hip_runtime.h>

#define Bsz 32
#define Nn  1024
#define Ff  128

// INSTRUMENTED ROUND: k1 body x6, gemm2 body x2 (idempotent repeats with
// memory-clobber fences) so both kernels exceed the ~84us harness-fill floor
// and appear in the top-5 rocprof rows with full counters. Outputs identical.

typedef __attribute__((ext_vector_type(8))) short bf16x8;
typedef __attribute__((ext_vector_type(4))) float f32x4;

static __device__ inline short f2bf(float f) {
    unsigned u = __builtin_bit_cast(unsigned, f);
    unsigned r = u + 0x7FFFu + ((u >> 16) & 1u);
    return (short)(r >> 16);
}

__global__ __launch_bounds__(256) void k0_wt(
    const float* __restrict__ w, short* __restrict__ wT)
{
    int gid = blockIdx.x * blockDim.x + threadIdx.x;
    if (gid < Ff * Ff) {
        int g = gid >> 7, k = gid & 127;
        wT[gid] = f2bf(w[k * Ff + g]);
    }
}

__global__ __launch_bounds__(256) void k1_fused(
    const float* __restrict__ feats,
    const short* __restrict__ wT,
    float* __restrict__ out_feats,
    short* __restrict__ fb,
    short* __restrict__ vw)
{
    const int row0 = blockIdx.x * 64;
    const int tid  = threadIdx.x;
    const int wid  = tid >> 6;
    const int lane = tid & 63;
    const int lr = lane & 15;
    const int kg = lane >> 4;

    for (int rep = 0; rep < 6; ++rep) {
        asm volatile("" ::: "memory");
        const int myrow = row0 + wid * 16 + lr;
        const float* frow = feats + (size_t)myrow * Ff;
        float* orow       = out_feats + (size_t)myrow * Ff;
        short* brow       = fb + (size_t)myrow * Ff;

        f32x4 acc[8] = {};

        for (int kc = 0; kc < 4; ++kc) {
            int k0 = kc * 32 + kg * 8;
            float4 v0 = ((const float4*)(frow + k0))[0];
            float4 v1 = ((const float4*)(frow + k0))[1];
            ((float4*)(orow + k0))[0] = v0;
            ((float4*)(orow + k0))[1] = v1;
            bf16x8 a = (bf16x8){ f2bf(v0.x), f2bf(v0.y), f2bf(v0.z), f2bf(v0.w),
                                 f2bf(v1.x), f2bf(v1.y), f2bf(v1.z), f2bf(v1.w) };
            *((bf16x8*)(brow + k0)) = a;
            for (int nf = 0; nf < 8; ++nf) {
                bf16x8 b = *((const bf16x8*)(wT + (size_t)(nf * 16 + lr) * Ff + k0));
                acc[nf] = __builtin_amdgcn_mfma_f32_16x16x32_bf16(a, b, acc[nf], 0, 0, 0);
            }
        }

        for (int nf = 0; nf < 8; ++nf) {
            int g = nf * 16 + lr;
            for (int r = 0; r < 4; ++r)
                vw[(size_t)(row0 + wid * 16 + kg * 4 + r) * Ff + g] = f2bf(acc[nf][r]);
        }
    }
}

__global__ __launch_bounds__(256) void gemm2_kernel(
    const short* __restrict__ vw,     // [B, N, F] bf16
    const short* __restrict__ fb,     // [B, N, F] bf16
    const float* __restrict__ bias,
    float* __restrict__ y)            // [B, N, N]
{
    // super-tile decode (r7)
    int blk   = blockIdx.x;
    int xcd   = blk & 7;
    int q     = blk >> 3;
    int chunk = q >> 4;
    int k     = q & 15;
    int super_id = chunk * 8 + xcd;
    int bidx  = super_id >> 2;
    int s     = super_id & 3;
    int sm = s >> 1, sn = s & 1;
    int mt = sm * 4 + (k >> 2);
    int nt = sn * 4 + (k & 3);

    int tid = threadIdx.x;
    int wid = tid >> 6, lane = tid & 63;
    int wm = wid >> 1, wn = wid & 1;
    int lr = lane & 15, kg = lane >> 4;

    for (int rep = 0; rep < 2; ++rep) {
        asm volatile("" ::: "memory");
        const short* A  = vw + (size_t)bidx * Nn * Ff;
        const short* Bp = fb + (size_t)bidx * Nn * Ff;
        int am0 = mt * 128 + wm * 64;
        int bn0 = nt * 128 + wn * 64;

        f32x4 acc[4][4] = {};

        for (int kc = 0; kc < 4; ++kc) {
            int k0 = kc * 32 + kg * 8;
            bf16x8 a[4], b[4];
            for (int mf = 0; mf < 4; ++mf)
                a[mf] = *((const bf16x8*)(A + (size_t)(am0 + mf * 16 + lr) * Ff + k0));
            for (int nf = 0; nf < 4; ++nf)
                b[nf] = *((const bf16x8*)(Bp + (size_t)(bn0 + nf * 16 + lr) * Ff + k0));
            for (int mf = 0; mf < 4; ++mf)
                for (int nf = 0; nf < 4; ++nf)
                    acc[mf][nf] = __builtin_amdgcn_mfma_f32_16x16x32_bf16(
                        a[mf], b[nf], acc[mf][nf], 0, 0, 0);
        }

        float bv = bias[0];
        float* Y = y + (size_t)bidx * Nn * Nn;
        for (int mf = 0; mf < 4; ++mf) {
            int row = am0 + mf * 16 + kg * 4;
            for (int nf = 0; nf < 4; ++nf) {
                int col = bn0 + nf * 16 + lr;
                float* p = Y + (size_t)row * Nn + col;
                for (int r = 0; r < 4; ++r)
                    p[(size_t)r * Nn] = acc[mf][nf][r] + bv;
            }
        }
    }
}

extern "C" void kernel_launch(void* const* d_in, const int* in_sizes, int n_in,
                              void* d_out, int out_size, void* d_ws, size_t ws_size,
                              hipStream_t stream) {
    const float* feats = (const float*)d_in[1];
    const float* w     = (const float*)d_in[2];
    const float* bias  = (const float*)d_in[3];
    float* y = (float*)d_out;
    float* out_feats = y + (size_t)Bsz * Nn * Nn;

    short* vw = (short*)d_ws;
    short* fb = vw + (size_t)Bsz * Nn * Ff;
    short* wT = fb + (size_t)Bsz * Nn * Ff;

    k0_wt<<<64, 256, 0, stream>>>(w, wT);
    k1_fused<<<512, 256, 0, stream>>>(feats, wT, out_feats, fb, vw);
    gemm2_kernel<<<2048, 256, 0, stream>>>(vw, fb, bias, y);
}

// Round 10
// 65.248 us; speedup vs baseline: 2.4640x; 2.4640x over previous
//
#include <hip/hip_runtime.h>

#define Bsz 32
#define Nn  1024
#define Ff  128

typedef __attribute__((ext_vector_type(8))) short bf16x8;
typedef __attribute__((ext_vector_type(4))) float f32x4;

// round-to-nearest-even f32 -> bf16 (bit pattern as short)
static __device__ inline short f2bf(float f) {
    unsigned u = __builtin_bit_cast(unsigned, f);
    unsigned r = u + 0x7FFFu + ((u >> 16) & 1u);
    return (short)(r >> 16);
}
static __device__ inline unsigned pack2(float lo, float hi) {
    return (unsigned)(unsigned short)f2bf(lo) | ((unsigned)(unsigned short)f2bf(hi) << 16);
}

// ---------------------------------------------------------------------------
// k1_fused_wt: (a) builds wT bf16 [g][k] in XOR-swizzled LDS from w (64 KB,
// L2-resident across blocks), (b) single feats read feeds the f32 passthrough
// copy (nontemporal — never re-read), the bf16 fb copy, and the MFMA
// A-fragments for vw = feats @ w. MFMA math identical to r3/r7's k1_fused,
// B-fragments now from LDS instead of global.
// Swizzle: byte ^= (row&7)<<4, same involution on write and read (rule 21).
// ---------------------------------------------------------------------------
__global__ __launch_bounds__(256) void k1_fused_wt(
    const float* __restrict__ feats,
    const float* __restrict__ w,
    float* __restrict__ out_feats,
    short* __restrict__ fb,
    short* __restrict__ vw)
{
    __shared__ short wT_lds[128 * 128];   // 32 KB, [g][k] bf16, swizzled

    const int tid  = threadIdx.x;
    const int wid  = tid >> 6;
    const int lane = tid & 63;
    const int lr = lane & 15;
    const int kg = lane >> 4;

    // ---- LDS wT fill: thread (g = tid>>1, khalf = (tid&1)*64) ----
    {
        const int g    = tid >> 1;
        const int kb   = (tid & 1) * 64;
        const int swzg = (g & 7) << 4;
        const size_t gofs = (size_t)g;
        for (int kk = 0; kk < 64; kk += 2) {
            int k = kb + kk;
            float lo = w[(size_t)k * Ff + gofs];
            float hi = w[(size_t)(k + 1) * Ff + gofs];
            unsigned pk = pack2(lo, hi);
            *(unsigned*)((char*)wT_lds + (g << 8) + ((k * 2) ^ swzg)) = pk;
        }
    }

    // ---- feats load + copies (issued before the barrier, overlaps fill) ----
    const int row0  = blockIdx.x * 64;
    const int myrow = row0 + wid * 16 + lr;
    const float* frow = feats + (size_t)myrow * Ff;
    float* orow       = out_feats + (size_t)myrow * Ff;
    short* brow       = fb + (size_t)myrow * Ff;

    bf16x8 a[4];
    for (int kc = 0; kc < 4; ++kc) {
        int k0 = kc * 32 + kg * 8;
        f32x4 v0 = ((const f32x4*)(frow + k0))[0];
        f32x4 v1 = ((const f32x4*)(frow + k0))[1];
        __builtin_nontemporal_store(v0, (f32x4*)(orow + k0));
        __builtin_nontemporal_store(v1, (f32x4*)(orow + k0) + 1);
        a[kc] = (bf16x8){ f2bf(v0[0]), f2bf(v0[1]), f2bf(v0[2]), f2bf(v0[3]),
                          f2bf(v1[0]), f2bf(v1[1]), f2bf(v1[2]), f2bf(v1[3]) };
        *((bf16x8*)(brow + k0)) = a[kc];          // re-read by gemm2: cacheable
    }
    __syncthreads();

    // ---- MFMA: vw rows = feats rows @ w ----
    f32x4 acc[8] = {};
    const int swz = (lr & 7) << 4;   // (row&7)<<4 with row = nf*16+lr
    for (int kc = 0; kc < 4; ++kc) {
        const int kbyte = kc * 64 + kg * 16;
        for (int nf = 0; nf < 8; ++nf) {
            const int row = nf * 16 + lr;
            bf16x8 b = *(const bf16x8*)((char*)wT_lds + (row << 8) + (kbyte ^ swz));
            acc[nf] = __builtin_amdgcn_mfma_f32_16x16x32_bf16(a[kc], b, acc[nf], 0, 0, 0);
        }
    }

    // C/D layout: col = lane&15, row = (lane>>4)*4 + reg  (verbatim r7)
    for (int nf = 0; nf < 8; ++nf) {
        int g = nf * 16 + lr;
        for (int r = 0; r < 4; ++r)
            vw[(size_t)(row0 + wid * 16 + kg * 4 + r) * Ff + g] = f2bf(acc[nf][r]);
    }
}

// ---------------------------------------------------------------------------
// gemm2: VERBATIM r7 (main loop, super-tile decode, epilogue addressing);
// only change: y stores are nontemporal (y is written once, never re-read —
// keeps A/B panels resident in each XCD's L2 instead of being evicted by
// 134 MB of write-allocate traffic).
// ---------------------------------------------------------------------------
__global__ __launch_bounds__(256) void gemm2_kernel(
    const short* __restrict__ vw,     // [B, N, F] bf16
    const short* __restrict__ fb,     // [B, N, F] bf16
    const float* __restrict__ bias,
    float* __restrict__ y)            // [B, N, N]
{
    int blk   = blockIdx.x;
    int xcd   = blk & 7;
    int q     = blk >> 3;
    int chunk = q >> 4;
    int k     = q & 15;
    int super_id = chunk * 8 + xcd;
    int bidx  = super_id >> 2;
    int s     = super_id & 3;
    int sm = s >> 1, sn = s & 1;
    int mt = sm * 4 + (k >> 2);
    int nt = sn * 4 + (k & 3);

    int tid = threadIdx.x;
    int wid = tid >> 6, lane = tid & 63;
    int wm = wid >> 1, wn = wid & 1;
    int lr = lane & 15, kg = lane >> 4;

    const short* A  = vw + (size_t)bidx * Nn * Ff;
    const short* Bp = fb + (size_t)bidx * Nn * Ff;
    int am0 = mt * 128 + wm * 64;
    int bn0 = nt * 128 + wn * 64;

    f32x4 acc[4][4] = {};

    for (int kc = 0; kc < 4; ++kc) {
        int k0 = kc * 32 + kg * 8;
        bf16x8 a[4], b[4];
        for (int mf = 0; mf < 4; ++mf)
            a[mf] = *((const bf16x8*)(A + (size_t)(am0 + mf * 16 + lr) * Ff + k0));
        for (int nf = 0; nf < 4; ++nf)
            b[nf] = *((const bf16x8*)(Bp + (size_t)(bn0 + nf * 16 + lr) * Ff + k0));
        for (int mf = 0; mf < 4; ++mf)
            for (int nf = 0; nf < 4; ++nf)
                acc[mf][nf] = __builtin_amdgcn_mfma_f32_16x16x32_bf16(
                    a[mf], b[nf], acc[mf][nf], 0, 0, 0);
    }

    float bv = bias[0];
    float* Y = y + (size_t)bidx * Nn * Nn;
    for (int mf = 0; mf < 4; ++mf) {
        int row = am0 + mf * 16 + kg * 4;
        for (int nf = 0; nf < 4; ++nf) {
            int col = bn0 + nf * 16 + lr;
            float* p = Y + (size_t)row * Nn + col;
            for (int r = 0; r < 4; ++r)
                __builtin_nontemporal_store(acc[mf][nf][r] + bv, p + (size_t)r * Nn);
        }
    }
}

extern "C" void kernel_launch(void* const* d_in, const int* in_sizes, int n_in,
                              void* d_out, int out_size, void* d_ws, size_t ws_size,
                              hipStream_t stream) {
    const float* feats = (const float*)d_in[1];
    const float* w     = (const float*)d_in[2];
    const float* bias  = (const float*)d_in[3];
    float* y = (float*)d_out;
    float* out_feats = y + (size_t)Bsz * Nn * Nn;

    short* vw = (short*)d_ws;
    short* fb = vw + (size_t)Bsz * Nn * Ff;

    k1_fused_wt<<<512, 256, 0, stream>>>(feats, w, out_feats, fb, vw);
    gemm2_kernel<<<2048, 256, 0, stream>>>(vw, fb, bias, y);
}